// Round 1
// baseline (136.238 us; speedup 1.0000x reference)
//
#include <hip/hip_runtime.h>
#include <cstdint>

// Problem dims (fixed by reference): B=4096, I=H=1024, K=I+H=2048, N=4H=4096
#define BROWS 4096
#define HDIM  1024
#define KTOT  2048
#define NTOT  4096

typedef __attribute__((ext_vector_type(4))) float  f32x4;
typedef __attribute__((ext_vector_type(8))) __bf16 bf16x8;
typedef __attribute__((ext_vector_type(8))) unsigned short u16x8;
typedef __attribute__((ext_vector_type(4))) unsigned short u16x4;

__device__ __forceinline__ unsigned short f2bf(float f) {
  uint32_t u = __float_as_uint(f);
  u += 0x7fffu + ((u >> 16) & 1u);   // RNE
  return (unsigned short)(u >> 16);
}
__device__ __forceinline__ float bf2f(unsigned short b) {
  return __uint_as_float(((uint32_t)b) << 16);
}

// ---------------------------------------------------------------------------
// Kernel 1: concat two [4096][1024] fp32 sources into one [4096][2048] bf16
// ---------------------------------------------------------------------------
__global__ __launch_bounds__(256) void concat_bf16_kernel(
    const float* __restrict__ s0, const float* __restrict__ s1,
    unsigned short* __restrict__ dst) {
  int64_t e = ((int64_t)blockIdx.x * 256 + threadIdx.x) * 8;  // 8 elems/thread
  int m = (int)(e >> 11);        // row (K=2048)
  int k = (int)(e & 2047);
  const float* src = (k < 1024) ? (s0 + (int64_t)m * 1024 + k)
                                : (s1 + (int64_t)m * 1024 + (k - 1024));
  f32x4 f0 = *(const f32x4*)(src);
  f32x4 f1 = *(const f32x4*)(src + 4);
  u16x8 v;
  v[0] = f2bf(f0[0]); v[1] = f2bf(f0[1]); v[2] = f2bf(f0[2]); v[3] = f2bf(f0[3]);
  v[4] = f2bf(f1[0]); v[5] = f2bf(f1[1]); v[6] = f2bf(f1[2]); v[7] = f2bf(f1[3]);
  *(u16x8*)(dst + e) = v;
}

// ---------------------------------------------------------------------------
// Kernel 2: C[4096][4096] (bf16) = A[4096][2048] @ B[4096][2048]^T
// m97 structure: 128x128 tile, 4 waves, BK=32, global_load_lds width 16
// ---------------------------------------------------------------------------
__device__ __forceinline__ void gload_lds16(const void* g, void* lds) {
  auto gp = reinterpret_cast<const __attribute__((address_space(1))) uint32_t*>(
      reinterpret_cast<uintptr_t>(g));
  auto lp = reinterpret_cast<__attribute__((address_space(3))) uint32_t*>(
      reinterpret_cast<uintptr_t>(lds));
  __builtin_amdgcn_global_load_lds(gp, lp, 16, 0, 0);
}

__global__ __launch_bounds__(256) void gemm_bt_kernel(
    const unsigned short* __restrict__ A,   // [4096][2048] bf16 row-major
    const unsigned short* __restrict__ B,   // [4096][2048] bf16 row-major (B^T)
    unsigned short* __restrict__ C) {       // [4096][4096] bf16
  __shared__ unsigned short As[128 * 32];   // 8 KB
  __shared__ unsigned short Bs[128 * 32];   // 8 KB

  const int tid  = threadIdx.x;
  const int lane = tid & 63;
  const int wid  = tid >> 6;
  const int bm = blockIdx.y, bn = blockIdx.x;

  // staging: chunk index == tid; row = tid>>2, 16B-col = tid&3; LDS linear.
  const int r0 = tid >> 2, c0 = tid & 3;
  const unsigned short* gA0 = A + ((int64_t)(bm * 128 + r0)) * KTOT + c0 * 8;
  const unsigned short* gA1 = gA0 + (int64_t)64 * KTOT;
  const unsigned short* gB0 = B + ((int64_t)(bn * 128 + r0)) * KTOT + c0 * 8;
  const unsigned short* gB1 = gB0 + (int64_t)64 * KTOT;

  const int wr = wid >> 1, wc = wid & 1;
  const int fr = lane & 15, fq = lane >> 4;

  f32x4 acc[4][4] = {};

  for (int kt = 0; kt < KTOT / 32; ++kt) {
    // ---- stage next K-slab into LDS (wave-uniform base + lane*16) ----
    gload_lds16(gA0, As + wid * 512);
    gload_lds16(gA1, As + 2048 + wid * 512);
    gload_lds16(gB0, Bs + wid * 512);
    gload_lds16(gB1, Bs + 2048 + wid * 512);
    gA0 += 32; gA1 += 32; gB0 += 32; gB1 += 32;
    __syncthreads();   // drains vmcnt before barrier (compiler-inserted)

    bf16x8 af[4], bfr[4];
#pragma unroll
    for (int i = 0; i < 4; ++i)
      af[i] = *(const bf16x8*)(As + (wr * 64 + i * 16 + fr) * 32 + fq * 8);
#pragma unroll
    for (int j = 0; j < 4; ++j)
      bfr[j] = *(const bf16x8*)(Bs + (wc * 64 + j * 16 + fr) * 32 + fq * 8);

#pragma unroll
    for (int i = 0; i < 4; ++i)
#pragma unroll
      for (int j = 0; j < 4; ++j)
        acc[i][j] = __builtin_amdgcn_mfma_f32_16x16x32_bf16(
            af[i], bfr[j], acc[i][j], 0, 0, 0);
    __syncthreads();
  }

  // epilogue: C/D layout col = lane&15, row = (lane>>4)*4 + reg
#pragma unroll
  for (int i = 0; i < 4; ++i)
#pragma unroll
    for (int j = 0; j < 4; ++j)
#pragma unroll
      for (int r = 0; r < 4; ++r) {
        int m = bm * 128 + wr * 64 + i * 16 + fq * 4 + r;
        int n = bn * 128 + wc * 64 + j * 16 + fr;
        C[(int64_t)m * NTOT + n] = f2bf(acc[i][j][r]);
      }
}

// ---------------------------------------------------------------------------
// Kernel 3: per-row LayerNorm x5 + LSTM pointwise; out = [hy, hy, cy]
// ---------------------------------------------------------------------------
__device__ __forceinline__ float2 block_meanvar(float s, float ss, float* sbuf,
                                                int lane, int wid) {
#pragma unroll
  for (int off = 32; off > 0; off >>= 1) {
    s  += __shfl_down(s, off);
    ss += __shfl_down(ss, off);
  }
  if (lane == 0) { sbuf[wid] = s; sbuf[4 + wid] = ss; }
  __syncthreads();
  if (threadIdx.x == 0) {
    float S  = sbuf[0] + sbuf[1] + sbuf[2] + sbuf[3];
    float SS = sbuf[4] + sbuf[5] + sbuf[6] + sbuf[7];
    float mean = S * (1.0f / 1024.0f);
    float var  = SS * (1.0f / 1024.0f) - mean * mean;
    var = fmaxf(var, 0.0f);
    float vf = (var < 1e-12f) ? 0.01f : 0.0f;
    sbuf[8] = mean;
    sbuf[9] = 1.0f / sqrtf(var + 1e-12f + vf);
  }
  __syncthreads();
  return make_float2(sbuf[8], sbuf[9]);
}

__device__ __forceinline__ float sigmoidf_(float x) {
  return 1.0f / (1.0f + expf(-x));
}

__global__ __launch_bounds__(256) void lstm_post_kernel(
    const unsigned short* __restrict__ gates,  // [4096][4096] bf16
    const float* __restrict__ cx,              // [4096][1024]
    const float* __restrict__ gamma,           // [5][1024]
    const float* __restrict__ beta,            // [5][1024]
    float* __restrict__ out) {                 // [3][4096][1024]
  __shared__ float sbuf[10];
  const int b = blockIdx.x;
  const int t = threadIdx.x;
  const int lane = t & 63, wid = t >> 6;
  const int h = t * 4;
  const unsigned short* grow = gates + (int64_t)b * 4096;

  float v[4][4];
#pragma unroll
  for (int g = 0; g < 4; ++g) {
    u16x4 raw = *(const u16x4*)(grow + g * 1024 + h);
#pragma unroll
    for (int j = 0; j < 4; ++j) v[g][j] = bf2f(raw[j]);
  }

  float act[4][4];
#pragma unroll
  for (int g = 0; g < 4; ++g) {
    float s  = v[g][0] + v[g][1] + v[g][2] + v[g][3];
    float ss = v[g][0]*v[g][0] + v[g][1]*v[g][1] + v[g][2]*v[g][2] + v[g][3]*v[g][3];
    float2 mv = block_meanvar(s, ss, sbuf, lane, wid);
    f32x4 gm = *(const f32x4*)(gamma + g * 1024 + h);
    f32x4 bt = *(const f32x4*)(beta  + g * 1024 + h);
#pragma unroll
    for (int j = 0; j < 4; ++j) {
      float n = (v[g][j] - mv.x) * mv.y * gm[j] + bt[j];
      if (g == 0)      act[g][j] = sigmoidf_(n);
      else if (g == 1) act[g][j] = sigmoidf_(n + 1.0f);   // FORGET_BIAS
      else if (g == 2) act[g][j] = tanhf(n);
      else             act[g][j] = sigmoidf_(n);
    }
  }

  f32x4 cxv = *(const f32x4*)(cx + (int64_t)b * 1024 + h);
  float cyr[4];
#pragma unroll
  for (int j = 0; j < 4; ++j)
    cyr[j] = act[1][j] * cxv[j] + act[0][j] * act[2][j];

  float s  = cyr[0] + cyr[1] + cyr[2] + cyr[3];
  float ss = cyr[0]*cyr[0] + cyr[1]*cyr[1] + cyr[2]*cyr[2] + cyr[3]*cyr[3];
  float2 mv = block_meanvar(s, ss, sbuf, lane, wid);
  f32x4 gm4 = *(const f32x4*)(gamma + 4 * 1024 + h);
  f32x4 bt4 = *(const f32x4*)(beta  + 4 * 1024 + h);

  f32x4 hy, cyn;
#pragma unroll
  for (int j = 0; j < 4; ++j) {
    float n = (cyr[j] - mv.x) * mv.y * gm4[j] + bt4[j];
    cyn[j] = n;
    hy[j]  = act[3][j] * tanhf(n);
  }

  const int64_t base = (int64_t)b * 1024 + h;
  *(f32x4*)(out + base)                       = hy;   // hy_dropped
  *(f32x4*)(out + (int64_t)4194304 + base)    = hy;   // hy
  *(f32x4*)(out + (int64_t)8388608 + base)    = cyn;  // cy
}

// ---------------------------------------------------------------------------
extern "C" void kernel_launch(void* const* d_in, const int* in_sizes, int n_in,
                              void* d_out, int out_size, void* d_ws, size_t ws_size,
                              hipStream_t stream) {
  (void)in_sizes; (void)n_in; (void)out_size; (void)ws_size;
  const float* x     = (const float*)d_in[0];
  const float* hx    = (const float*)d_in[1];
  const float* cx    = (const float*)d_in[2];
  const float* wih   = (const float*)d_in[3];
  const float* whh   = (const float*)d_in[4];
  const float* gamma = (const float*)d_in[5];
  const float* beta  = (const float*)d_in[6];
  float* out = (float*)d_out;

  unsigned short* Abf   = (unsigned short*)d_ws;            // [4096][2048] bf16, 16MB
  unsigned short* Bbf   = Abf + (size_t)4096 * 2048;        // [4096][2048] bf16, 16MB
  unsigned short* gates = Bbf + (size_t)4096 * 2048;        // [4096][4096] bf16, 32MB

  concat_bf16_kernel<<<4096, 256, 0, stream>>>(x,   hx,  Abf);
  concat_bf16_kernel<<<4096, 256, 0, stream>>>(wih, whh, Bbf);
  gemm_bt_kernel<<<dim3(32, 32), 256, 0, stream>>>(Abf, Bbf, gates);
  lstm_post_kernel<<<4096, 256, 0, stream>>>(gates, cx, gamma, beta, out);
}

// Round 5
// 118.262 us; speedup vs baseline: 1.1520x; 1.1520x over previous
//
#include <hip/hip_runtime.h>
#include <cstdint>

// Problem dims (fixed by reference): B=4096, I=H=1024, K=I+H=2048, N=4H=4096
#define KTOT  2048
#define NTOT  4096

typedef __attribute__((ext_vector_type(4))) float  f32x4;
typedef __attribute__((ext_vector_type(8))) __bf16 bf16x8;
typedef __attribute__((ext_vector_type(8))) unsigned short u16x8;
typedef __attribute__((ext_vector_type(4))) unsigned short u16x4;

__device__ __forceinline__ unsigned short f2bf(float f) {
  uint32_t u = __float_as_uint(f);
  u += 0x7fffu + ((u >> 16) & 1u);   // RNE
  return (unsigned short)(u >> 16);
}
__device__ __forceinline__ float bf2f(unsigned short b) {
  return __uint_as_float(((uint32_t)b) << 16);
}

// ---------------------------------------------------------------------------
// Kernel 1: concat two [4096][1024] fp32 sources into one [4096][2048] bf16
// (verified r1)
// ---------------------------------------------------------------------------
__global__ __launch_bounds__(256) void concat_bf16_kernel(
    const float* __restrict__ s0, const float* __restrict__ s1,
    unsigned short* __restrict__ dst) {
  int64_t e = ((int64_t)blockIdx.x * 256 + threadIdx.x) * 8;  // 8 elems/thread
  int m = (int)(e >> 11);        // row (K=2048)
  int k = (int)(e & 2047);
  const float* src = (k < 1024) ? (s0 + (int64_t)m * 1024 + k)
                                : (s1 + (int64_t)m * 1024 + (k - 1024));
  f32x4 f0 = *(const f32x4*)(src);
  f32x4 f1 = *(const f32x4*)(src + 4);
  u16x8 v;
  v[0] = f2bf(f0[0]); v[1] = f2bf(f0[1]); v[2] = f2bf(f0[2]); v[3] = f2bf(f0[3]);
  v[4] = f2bf(f1[0]); v[5] = f2bf(f1[1]); v[6] = f2bf(f1[2]); v[7] = f2bf(f1[3]);
  *(u16x8*)(dst + e) = v;
}

// ---------------------------------------------------------------------------
// Kernel 2: C[4096][4096] (bf16) = A[4096][2048] @ B[4096][2048]^T
// Round-1 verified template (stage -> sync -> read -> MFMA -> sync), with two
// in-envelope deltas: BK 32->64 (half the barrier pairs) and a 3-bit XOR
// k-swizzle (slot ^= row&7) so the BK=64 fragment read stays uniform across
// bank-quads.  LDS dest stays LINEAR (global_load_lds requirement); the
// swizzle is applied as inverse-permuted GLOBAL source + permuted READ slot.
// ---------------------------------------------------------------------------
__device__ __forceinline__ void gload_lds16(const void* g, void* lds_p) {
  auto gp = reinterpret_cast<const __attribute__((address_space(1))) uint32_t*>(
      reinterpret_cast<uintptr_t>(g));
  auto lp = reinterpret_cast<__attribute__((address_space(3))) uint32_t*>(
      reinterpret_cast<uintptr_t>(lds_p));
  __builtin_amdgcn_global_load_lds(gp, lp, 16, 0, 0);
}

__global__ __launch_bounds__(256) void gemm_bt_kernel(
    const unsigned short* __restrict__ A,   // [4096][2048] bf16 row-major
    const unsigned short* __restrict__ B,   // [4096][2048] bf16 row-major (B^T)
    unsigned short* __restrict__ C) {       // [4096][4096] bf16
  __shared__ unsigned short As[128 * 64];   // 16 KB
  __shared__ unsigned short Bs[128 * 64];   // 16 KB

  const int tid  = threadIdx.x;
  const int lane = tid & 63;
  const int wid  = tid >> 6;
  const int bm = blockIdx.y, bn = blockIdx.x;

  // ---- staging: thread covers LDS row r0 = tid>>3, k-octet c0 = tid&7 ----
  // LDS is linear [row][64]; global source fetches octet (c0 ^ (row&7)) so
  // that LDS slot j' holds logical octet j' ^ (row&7)  (XOR involution).
  const int r0 = tid >> 3, c0 = tid & 7;
  const int kcol = ((c0 ^ (r0 & 7)) * 8);
  const unsigned short* gA[4];
  const unsigned short* gB[4];
#pragma unroll
  for (int s = 0; s < 4; ++s) {
    gA[s] = A + ((int64_t)(bm * 128 + s * 32 + r0)) * KTOT + kcol;
    gB[s] = B + ((int64_t)(bn * 128 + s * 32 + r0)) * KTOT + kcol;
  }

  const int wr = wid >> 1, wc = wid & 1;   // 2x2 waves, 64x64 output each
  const int fr = lane & 15, fq = lane >> 4;

  // ---- swizzled read slots: logical k = ks*32 + fq*8 lives at slot
  //      j'(ks) = (ks*4 + fq) ^ (fr&7)   (row&7 == fr&7 for frag rows) ----
  const int jsw0 = ((fq) ^ (fr & 7)) * 8;
  const int jsw1 = ((4 + fq) ^ (fr & 7)) * 8;
  const unsigned short* aB0 = As + (wr * 64 + fr) * 64 + jsw0;
  const unsigned short* aB1 = As + (wr * 64 + fr) * 64 + jsw1;
  const unsigned short* bB0 = Bs + (wc * 64 + fr) * 64 + jsw0;
  const unsigned short* bB1 = Bs + (wc * 64 + fr) * 64 + jsw1;

  f32x4 acc[4][4] = {};

  for (int kt = 0; kt < KTOT / 64; ++kt) {
    // ---- stage K-slab kt into LDS (linear dest: wave base + lane*16) ----
#pragma unroll
    for (int s = 0; s < 4; ++s) {
      gload_lds16(gA[s], As + s * 2048 + wid * 512);
      gload_lds16(gB[s], Bs + s * 2048 + wid * 512);
      gA[s] += 64; gB[s] += 64;
    }
    __syncthreads();   // compiler drains vmcnt before barrier

    bf16x8 af[4][2], bfr[4][2];
#pragma unroll
    for (int i = 0; i < 4; ++i) {
      af[i][0]  = *(const bf16x8*)(aB0 + i * 1024);
      af[i][1]  = *(const bf16x8*)(aB1 + i * 1024);
      bfr[i][0] = *(const bf16x8*)(bB0 + i * 1024);
      bfr[i][1] = *(const bf16x8*)(bB1 + i * 1024);
    }

#pragma unroll
    for (int ks = 0; ks < 2; ++ks)
#pragma unroll
      for (int i = 0; i < 4; ++i)
#pragma unroll
        for (int j = 0; j < 4; ++j)
          acc[i][j] = __builtin_amdgcn_mfma_f32_16x16x32_bf16(
              af[i][ks], bfr[j][ks], acc[i][j], 0, 0, 0);
    __syncthreads();
  }

  // ---- epilogue (r1-verified): col = lane&15, row = (lane>>4)*4 + reg ----
#pragma unroll
  for (int i = 0; i < 4; ++i)
#pragma unroll
    for (int j = 0; j < 4; ++j)
#pragma unroll
      for (int r = 0; r < 4; ++r) {
        int m = bm * 128 + wr * 64 + i * 16 + fq * 4 + r;
        int n = bn * 128 + wc * 64 + j * 16 + fr;
        C[(int64_t)m * NTOT + n] = f2bf(acc[i][j][r]);
      }
}

// ---------------------------------------------------------------------------
// Kernel 3: per-row LayerNorm x5 + LSTM pointwise; out = [hy, hy, cy]
// (verified r1)
// ---------------------------------------------------------------------------
__device__ __forceinline__ float2 block_meanvar(float s, float ss, float* sbuf,
                                                int lane, int wid) {
#pragma unroll
  for (int off = 32; off > 0; off >>= 1) {
    s  += __shfl_down(s, off);
    ss += __shfl_down(ss, off);
  }
  if (lane == 0) { sbuf[wid] = s; sbuf[4 + wid] = ss; }
  __syncthreads();
  if (threadIdx.x == 0) {
    float S  = sbuf[0] + sbuf[1] + sbuf[2] + sbuf[3];
    float SS = sbuf[4] + sbuf[5] + sbuf[6] + sbuf[7];
    float mean = S * (1.0f / 1024.0f);
    float var  = SS * (1.0f / 1024.0f) - mean * mean;
    var = fmaxf(var, 0.0f);
    float vf = (var < 1e-12f) ? 0.01f : 0.0f;
    sbuf[8] = mean;
    sbuf[9] = 1.0f / sqrtf(var + 1e-12f + vf);
  }
  __syncthreads();
  return make_float2(sbuf[8], sbuf[9]);
}

__device__ __forceinline__ float sigmoidf_(float x) {
  return 1.0f / (1.0f + expf(-x));
}

__global__ __launch_bounds__(256) void lstm_post_kernel(
    const unsigned short* __restrict__ gates,  // [4096][4096] bf16
    const float* __restrict__ cx,              // [4096][1024]
    const float* __restrict__ gamma,           // [5][1024]
    const float* __restrict__ beta,            // [5][1024]
    float* __restrict__ out) {                 // [3][4096][1024]
  __shared__ float sbuf[10];
  const int b = blockIdx.x;
  const int t = threadIdx.x;
  const int lane = t & 63, wid = t >> 6;
  const int h = t * 4;
  const unsigned short* grow = gates + (int64_t)b * 4096;

  float v[4][4];
#pragma unroll
  for (int g = 0; g < 4; ++g) {
    u16x4 raw = *(const u16x4*)(grow + g * 1024 + h);
#pragma unroll
    for (int j = 0; j < 4; ++j) v[g][j] = bf2f(raw[j]);
  }

  float act[4][4];
#pragma unroll
  for (int g = 0; g < 4; ++g) {
    float s  = v[g][0] + v[g][1] + v[g][2] + v[g][3];
    float ss = v[g][0]*v[g][0] + v[g][1]*v[g][1] + v[g][2]*v[g][2] + v[g][3]*v[g][3];
    float2 mv = block_meanvar(s, ss, sbuf, lane, wid);
    f32x4 gm = *(const f32x4*)(gamma + g * 1024 + h);
    f32x4 bt = *(const f32x4*)(beta  + g * 1024 + h);
#pragma unroll
    for (int j = 0; j < 4; ++j) {
      float n = (v[g][j] - mv.x) * mv.y * gm[j] + bt[j];
      if (g == 0)      act[g][j] = sigmoidf_(n);
      else if (g == 1) act[g][j] = sigmoidf_(n + 1.0f);   // FORGET_BIAS
      else if (g == 2) act[g][j] = tanhf(n);
      else             act[g][j] = sigmoidf_(n);
    }
  }

  f32x4 cxv = *(const f32x4*)(cx + (int64_t)b * 1024 + h);
  float cyr[4];
#pragma unroll
  for (int j = 0; j < 4; ++j)
    cyr[j] = act[1][j] * cxv[j] + act[0][j] * act[2][j];

  float s  = cyr[0] + cyr[1] + cyr[2] + cyr[3];
  float ss = cyr[0]*cyr[0] + cyr[1]*cyr[1] + cyr[2]*cyr[2] + cyr[3]*cyr[3];
  float2 mv = block_meanvar(s, ss, sbuf, lane, wid);
  f32x4 gm4 = *(const f32x4*)(gamma + 4 * 1024 + h);
  f32x4 bt4 = *(const f32x4*)(beta  + 4 * 1024 + h);

  f32x4 hy, cyn;
#pragma unroll
  for (int j = 0; j < 4; ++j) {
    float n = (cyr[j] - mv.x) * mv.y * gm4[j] + bt4[j];
    cyn[j] = n;
    hy[j]  = act[3][j] * tanhf(n);
  }

  const int64_t base = (int64_t)b * 1024 + h;
  *(f32x4*)(out + base)                       = hy;   // hy_dropped
  *(f32x4*)(out + (int64_t)4194304 + base)    = hy;   // hy
  *(f32x4*)(out + (int64_t)8388608 + base)    = cyn;  // cy
}

// ---------------------------------------------------------------------------
extern "C" void kernel_launch(void* const* d_in, const int* in_sizes, int n_in,
                              void* d_out, int out_size, void* d_ws, size_t ws_size,
                              hipStream_t stream) {
  (void)in_sizes; (void)n_in; (void)out_size; (void)ws_size;
  const float* x     = (const float*)d_in[0];
  const float* hx    = (const float*)d_in[1];
  const float* cx    = (const float*)d_in[2];
  const float* wih   = (const float*)d_in[3];
  const float* whh   = (const float*)d_in[4];
  const float* gamma = (const float*)d_in[5];
  const float* beta  = (const float*)d_in[6];
  float* out = (float*)d_out;

  unsigned short* Abf   = (unsigned short*)d_ws;            // [4096][2048] bf16, 16MB
  unsigned short* Bbf   = Abf + (size_t)4096 * 2048;        // [4096][2048] bf16, 16MB
  unsigned short* gates = Bbf + (size_t)4096 * 2048;        // [4096][4096] bf16, 32MB

  concat_bf16_kernel<<<4096, 256, 0, stream>>>(x,   hx,  Abf);
  concat_bf16_kernel<<<4096, 256, 0, stream>>>(wih, whh, Bbf);
  gemm_bt_kernel<<<dim3(32, 32), 256, 0, stream>>>(Abf, Bbf, gates);
  lstm_post_kernel<<<4096, 256, 0, stream>>>(gates, cx, gamma, beta, out);
}